// Round 5
// baseline (3322.573 us; speedup 1.0000x reference)
//
#include <hip/hip_runtime.h>
#include <math.h>

#define B_ 64
#define T_ 2048
#define E_ 128
#define H_ 128
#define G3_ 384   // 3*H
#define C_ 32
#define M_ (T_ * B_)   // 131072 tokens

typedef _Float16 f16x2 __attribute__((ext_vector_type(2)));

__device__ __forceinline__ f16x2 as_h2(unsigned int u) {
    union { unsigned int u; f16x2 h; } c; c.u = u; return c.h;
}

#if __has_builtin(__builtin_amdgcn_fdot2)
__device__ __forceinline__ float fdot2_acc(f16x2 a, f16x2 b, float c) {
    return __builtin_amdgcn_fdot2(a, b, c, false);
}
#else
__device__ __forceinline__ float fdot2_acc(f16x2 a, f16x2 b, float c) {
    return fmaf((float)a.y, (float)b.y, fmaf((float)a.x, (float)b.x, c));
}
#endif

// ---------------------------------------------------------------------------
// K1/K3: gi[m][g] = bias[g] + dot(w[g][:], row_m[:]) ; m = t*B + b
// GATHER: row_m = emb[x[b*T+t]] ; else row_m = src[m]
// r=3 f16 weight-stationary (round-4 version, ~165 µs each).
// ---------------------------------------------------------------------------
template <bool GATHER>
__global__ __launch_bounds__(128, 1) void gates_gemm(
    const float* __restrict__ src,   // emb [V,128] or y [M,128]
    const int*   __restrict__ xidx,  // x [B,T] or nullptr
    const float* __restrict__ w,     // [384,128]
    const float* __restrict__ bias,  // [384]
    float* __restrict__ gi)          // [M,384]
{
    const int g = threadIdx.x;  // 0..127
    f16x2 wr[3][64];
#pragma unroll
    for (int r = 0; r < 3; r++) {
        const float2* w2 = (const float2*)(w + (g + 128 * r) * 128);
#pragma unroll
        for (int i = 0; i < 64; i++) {
            float2 v = w2[i];
            wr[r][i] = (f16x2){(_Float16)v.x, (_Float16)v.y};
        }
    }
    const float bg0 = bias[g], bg1 = bias[g + 128], bg2 = bias[g + 256];

    __shared__ __align__(16) f16x2 rows[8][64];   // 8 tokens x 128 f16

    for (int grp = blockIdx.x; grp < M_ / 8; grp += gridDim.x) {
        const int m0 = grp * 8;
        __syncthreads();  // protect rows[] from readers of previous iter
#pragma unroll
        for (int k = 0; k < 4; k++) {
            const int j = g + 128 * k;          // 0..511 (f16x2 slots)
            const int s = j >> 6;               // token in group
            const int p = j & 63;               // f16x2 pair within row
            const int mm = m0 + s;
            long row;
            if (GATHER) {
                const int t = mm >> 6;          // m = t*B + b, B=64
                const int b = mm & 63;
                row = (long)xidx[b * T_ + t];
            } else {
                row = mm;
            }
            float2 v = ((const float2*)(src + row * 128))[p];
            rows[s][p] = (f16x2){(_Float16)v.x, (_Float16)v.y};
        }
        __syncthreads();
        for (int s = 0; s < 8; s++) {
            const uint4* h16 = (const uint4*)rows[s];
            float a00 = bg0, a01 = 0.f, a10 = bg1, a11 = 0.f, a20 = bg2, a21 = 0.f;
#pragma unroll
            for (int i = 0; i < 16; i++) {
                uint4 u = h16[i];
                f16x2 ux = as_h2(u.x), uy = as_h2(u.y), uz = as_h2(u.z), uw = as_h2(u.w);
                a00 = fdot2_acc(wr[0][4*i+0], ux, a00);
                a10 = fdot2_acc(wr[1][4*i+0], ux, a10);
                a20 = fdot2_acc(wr[2][4*i+0], ux, a20);
                a01 = fdot2_acc(wr[0][4*i+1], uy, a01);
                a11 = fdot2_acc(wr[1][4*i+1], uy, a11);
                a21 = fdot2_acc(wr[2][4*i+1], uy, a21);
                a00 = fdot2_acc(wr[0][4*i+2], uz, a00);
                a10 = fdot2_acc(wr[1][4*i+2], uz, a10);
                a20 = fdot2_acc(wr[2][4*i+2], uz, a20);
                a01 = fdot2_acc(wr[0][4*i+3], uw, a01);
                a11 = fdot2_acc(wr[1][4*i+3], uw, a11);
                a21 = fdot2_acc(wr[2][4*i+3], uw, a21);
            }
            float* go = gi + (long)(m0 + s) * G3_ + g;
            go[0]   = a00 + a01;
            go[128] = a10 + a11;
            go[256] = a20 + a21;
        }
    }
}

// ---------------------------------------------------------------------------
// K2/K4: GRU recurrence. One block per batch element, 128 threads (2 waves).
// Thread g owns w_hh rows {g, g+128, g+256} (192 f16x2 VGPRs); gate math
// fully in-thread; h f16 double-buffered in LDS, one barrier/step.
// NEW (round 5): gi loads software-pipelined one step ahead — round-4
// counters showed the ~900-cyc global-load latency sat on the serial
// critical path (1560 cyc/step with all pipes <25% busy).
// ---------------------------------------------------------------------------
__global__ __launch_bounds__(128, 1) void gru_layer(
    const float* __restrict__ gi,    // [M,384]
    const float* __restrict__ w_hh,  // [384,128]
    const float* __restrict__ b_hh,  // [384]
    float* __restrict__ y)           // [M,128]
{
    const int g = threadIdx.x;  // h-dim 0..127
    const int b = blockIdx.x;

    f16x2 wr[3][64];
#pragma unroll
    for (int r = 0; r < 3; r++) {
        const float2* w2 = (const float2*)(w_hh + (g + 128 * r) * 128);
#pragma unroll
        for (int i = 0; i < 64; i++) {
            float2 v = w2[i];
            wr[r][i] = (f16x2){(_Float16)v.x, (_Float16)v.y};
        }
    }
    const float bg0 = b_hh[g], bg1 = b_hh[g + 128], bg2 = b_hh[g + 256];

    __shared__ __align__(16) f16x2 hb[2][64];   // double-buffered h (f16)

    float h_own = 0.f;
    if (g < 64) hb[0][g] = (f16x2){(_Float16)0.f, (_Float16)0.f};
    __syncthreads();

    const float* gi_b = gi + (long)b * G3_;
    float* y_b = y + (long)b * H_;

    // preamble: gates for step 0
    float ir = gi_b[g], iz = gi_b[128 + g], inn = gi_b[256 + g];

    for (int t = 0; t < T_; t++) {
        // prefetch next step's input gates (consumed AFTER next dot -> ~900+
        // cycles of cover; hides even a full HBM miss)
        float ir_n = 0.f, iz_n = 0.f, inn_n = 0.f;
        if (t + 1 < T_) {
            const float* gi_n = gi_b + (long)(t + 1) * (B_ * G3_);
            ir_n = gi_n[g];
            iz_n = gi_n[128 + g];
            inn_n = gi_n[256 + g];
        }

        const uint4* h16 = (const uint4*)hb[t & 1];
        float a00 = bg0, a01 = 0.f, a10 = bg1, a11 = 0.f, a20 = bg2, a21 = 0.f;
#pragma unroll
        for (int i = 0; i < 16; i++) {
            uint4 u = h16[i];
            f16x2 ux = as_h2(u.x), uy = as_h2(u.y), uz = as_h2(u.z), uw = as_h2(u.w);
            a00 = fdot2_acc(wr[0][4*i+0], ux, a00);
            a10 = fdot2_acc(wr[1][4*i+0], ux, a10);
            a20 = fdot2_acc(wr[2][4*i+0], ux, a20);
            a01 = fdot2_acc(wr[0][4*i+1], uy, a01);
            a11 = fdot2_acc(wr[1][4*i+1], uy, a11);
            a21 = fdot2_acc(wr[2][4*i+1], uy, a21);
            a00 = fdot2_acc(wr[0][4*i+2], uz, a00);
            a10 = fdot2_acc(wr[1][4*i+2], uz, a10);
            a20 = fdot2_acc(wr[2][4*i+2], uz, a20);
            a01 = fdot2_acc(wr[0][4*i+3], uw, a01);
            a11 = fdot2_acc(wr[1][4*i+3], uw, a11);
            a21 = fdot2_acc(wr[2][4*i+3], uw, a21);
        }
        const float hr = a00 + a01;
        const float hz = a10 + a11;
        const float hn = a20 + a21;

        const float r = 1.f / (1.f + __expf(-(ir + hr)));
        const float z = 1.f / (1.f + __expf(-(iz + hz)));
        const float narg = inn + r * hn;
        const float n = 1.f - 2.f / (__expf(2.f * narg) + 1.f);  // tanh
        h_own = (1.f - z) * n + z * h_own;

        ((_Float16*)hb[(t + 1) & 1])[g] = (_Float16)h_own;  // write OTHER buffer
        y_b[(long)t * (B_ * H_) + g] = h_own;
        __syncthreads();   // single barrier: writes visible before next reads

        ir = ir_n; iz = iz_n; inn = inn_n;
    }
}

// ---------------------------------------------------------------------------
// K5: out[b*T+t][c] = relu(fc_b[c] + dot(fc_w[c], y[t*B+b]))
// ---------------------------------------------------------------------------
__global__ __launch_bounds__(256, 2) void fc_relu(
    const float* __restrict__ y,     // [M,128]
    const float* __restrict__ fc_w,  // [32,128]
    const float* __restrict__ fc_b,  // [32]
    float* __restrict__ out)         // [B*T,32]
{
    const int tid = threadIdx.x;
    const int c = tid & 31;
    const int slot = tid >> 5;

    float4 wr[32];
    const float4* w4 = (const float4*)(fc_w + c * 128);
#pragma unroll
    for (int i = 0; i < 32; i++) wr[i] = w4[i];
    const float bc = fc_b[c];

    __shared__ __align__(16) float rows[8][128];

    for (int grp = blockIdx.x; grp < M_ / 8; grp += gridDim.x) {
        const int m0 = grp * 8;
        __syncthreads();
        for (int i = tid; i < 8 * 128; i += 256) {
            rows[i >> 7][i & 127] = y[(long)m0 * 128 + i];
        }
        __syncthreads();
        const float4* h4 = (const float4*)rows[slot];
        float a0 = bc, a1 = 0.f, a2 = 0.f, a3 = 0.f;
#pragma unroll
        for (int i = 0; i < 32; i += 4) {
            float4 h0 = h4[i], h1 = h4[i + 1], h2 = h4[i + 2], h3 = h4[i + 3];
            a0 = fmaf(wr[i].w, h0.w, fmaf(wr[i].z, h0.z, fmaf(wr[i].y, h0.y, fmaf(wr[i].x, h0.x, a0))));
            a1 = fmaf(wr[i+1].w, h1.w, fmaf(wr[i+1].z, h1.z, fmaf(wr[i+1].y, h1.y, fmaf(wr[i+1].x, h1.x, a1))));
            a2 = fmaf(wr[i+2].w, h2.w, fmaf(wr[i+2].z, h2.z, fmaf(wr[i+2].y, h2.y, fmaf(wr[i+2].x, h2.x, a2))));
            a3 = fmaf(wr[i+3].w, h3.w, fmaf(wr[i+3].z, h3.z, fmaf(wr[i+3].y, h3.y, fmaf(wr[i+3].x, h3.x, a3))));
        }
        float acc = (a0 + a1) + (a2 + a3);
        acc = fmaxf(acc, 0.f);
        const int m = m0 + slot;
        const int t = m >> 6;
        const int b = m & 63;
        out[((long)b * T_ + t) * C_ + c] = acc;
    }
}

// ---------------------------------------------------------------------------
extern "C" void kernel_launch(void* const* d_in, const int* in_sizes, int n_in,
                              void* d_out, int out_size, void* d_ws, size_t ws_size,
                              hipStream_t stream) {
    const int*   x     = (const int*)d_in[0];
    const float* emb   = (const float*)d_in[1];
    const float* w_ih0 = (const float*)d_in[2];
    const float* w_hh0 = (const float*)d_in[3];
    const float* b_ih0 = (const float*)d_in[4];
    const float* b_hh0 = (const float*)d_in[5];
    const float* w_ih1 = (const float*)d_in[6];
    const float* w_hh1 = (const float*)d_in[7];
    const float* b_ih1 = (const float*)d_in[8];
    const float* b_hh1 = (const float*)d_in[9];
    const float* fc_w  = (const float*)d_in[10];
    const float* fc_b  = (const float*)d_in[11];
    float* out = (float*)d_out;

    // workspace: gi [M,384] fp32 (201.3 MB, reused for both layers) + y [M,128] (67.1 MB)
    float* gi = (float*)d_ws;
    float* yb = (float*)((char*)d_ws + (size_t)M_ * G3_ * sizeof(float));

    // layer 0 input gates (embedding gather fused)
    gates_gemm<true><<<512, 128, 0, stream>>>(emb, x, w_ih0, b_ih0, gi);
    // layer 0 recurrence
    gru_layer<<<B_, 128, 0, stream>>>(gi, w_hh0, b_hh0, yb);
    // layer 1 input gates
    gates_gemm<false><<<512, 128, 0, stream>>>(yb, nullptr, w_ih1, b_ih1, gi);
    // layer 1 recurrence (overwrites yb; gi1 already computed)
    gru_layer<<<B_, 128, 0, stream>>>(gi, w_hh1, b_hh1, yb);
    // FC + ReLU
    fc_relu<<<512, 256, 0, stream>>>(yb, fc_w, fc_b, out);
}